// Round 14
// baseline (104.097 us; speedup 1.0000x reference)
//
#include <hip/hip_runtime.h>
#include <hip/hip_bf16.h>

#define NEGV (-10000.0f)
#define EPSV (1e-5f)
#define NINF (-3.4e38f)

typedef __attribute__((ext_vector_type(8))) short short8;
typedef __attribute__((ext_vector_type(4))) float floatx4;

constexpr int Bsz = 4096, Nv = 64, Hd = 128, DEPTH = 3, H2 = 64;
constexpr int ESTR = 72;   // enc row stride bf16: 144 B (b128-aligned rows)

struct alignas(8) BH4 { __hip_bfloat162 a, b; };

__device__ __forceinline__ unsigned short f2b(float f) {
    unsigned int u = __builtin_bit_cast(unsigned int, f);
    u += 0x7fffu + ((u >> 16) & 1u);          // RNE to bf16
    return (unsigned short)(u >> 16);
}
__device__ __forceinline__ float b2f(short s) {
    unsigned int u = ((unsigned int)(unsigned short)s) << 16;
    return __builtin_bit_cast(float, u);
}

// 16-lane all-reduce sum on the VALU via DPP (no LDS pipe)
template <int CTRL>
__device__ __forceinline__ float dpp_add(float v) {
    int y = __builtin_amdgcn_update_dpp(0, __builtin_bit_cast(int, v), CTRL, 0xf, 0xf, true);
    return v + __builtin_bit_cast(float, y);
}
__device__ __forceinline__ float sum16(float v) {
    v = dpp_add<0xB1>(v);    // quad_perm [1,0,3,2]  (xor 1)
    v = dpp_add<0x4E>(v);    // quad_perm [2,3,0,1]  (xor 2)
    v = dpp_add<0x124>(v);   // row_ror:4
    v = dpp_add<0x128>(v);   // row_ror:8
    return v;
}

// top-2 helpers (duplicate-preserving, matches jax top_k semantics)
__device__ __forceinline__ void t2ins(float& t1, float& t2, float v) {
    float lo = fminf(t1, v); t1 = fmaxf(t1, v); t2 = fmaxf(t2, lo);
}
__device__ __forceinline__ void t2merge(float& t1, float& t2, float o1, float o2) {
    float lo = fminf(t1, o1); t1 = fmaxf(t1, o1); t2 = fmaxf(fmaxf(t2, o2), lo);
}

// Pack W[l] (128x64 f32) into bf16 MFMA-fragment order WITH column permutation:
// fragment position (ct,lr) sources actual column 4*lr+ct, so D-lane lr owns
// 4 consecutive output columns across its 4 accumulators.
__global__ void prep_w(const float* __restrict__ Ws, unsigned short* __restrict__ wt) {
    int idx = blockIdx.x * 256 + threadIdx.x;
    if (idx < DEPTH * 8192) {
        int l = idx >> 13, o = idx & 8191;
        int j = o & 7, q = (o >> 3) & 63, hi = (o >> 9) & 3, kt = o >> 11;
        int k = kt * 32 + hi * 8 + j;
        int srccol = (q & 15) * 4 + (q >> 4);
        wt[idx] = f2b(Ws[l * 8192 + k * 64 + srccol]);
    }
}

__global__ __launch_bounds__(256, 6)
void subgraph_kernel(const float* __restrict__ hidden, const int* __restrict__ lvn,
                     const unsigned short* __restrict__ wt,
                     const float* __restrict__ bsv, const float* __restrict__ lnw,
                     const float* __restrict__ lnb, float* __restrict__ out)
{
    // block = 1 polyline, 4 waves, wave w owns rows w*16..w*16+15.
    // enc is wave-local (A rows == rows the wave wrote). Only (f1,f2) crosses waves.
    __shared__ __hip_bfloat16 encw_all[4][16][ESTR];  // 9216 B
    __shared__ float fbuf[2][4][128];                 // 4096 B: per-wave partial (f1,f2) pairs
    __shared__ float obuf[4][128];                    // 2048 B: per-wave enc/loo maxes

    const int t = threadIdx.x;
    const int lane = t & 63, wid = t >> 6;
    const int b = blockIdx.x;
    const int lr = lane & 15, hi = lane >> 4;
    const int L = lvn[b];

    __hip_bfloat16 (*encw)[ESTR] = encw_all[wid];
    const int arowg = wid * 16 + lr;                  // this lane's A-row (global row)
    const float maddA = (arowg >= L) ? NEGV : 0.0f;

    const float4* ab = (const float4*)(hidden + (size_t)b * Nv * Hd);
    float em[4], lm[4];                               // set at l==2

#pragma unroll
    for (int l = 0; l < DEPTH; ++l) {
        const short8* wfrag = (const short8*)(wt + l * 8192);

        // ---- A fragments ----
        short8 af[4];
        if (l == 0) {
#pragma unroll
            for (int kt = 0; kt < 4; ++kt) {
                int fi = arowg * 32 + kt * 8 + hi * 2;
                float4 f0 = ab[fi], f1 = ab[fi + 1];
                union { short8 s; __hip_bfloat162 h[4]; } u;
                u.h[0] = __float22bfloat162_rn(make_float2(f0.x, f0.y));
                u.h[1] = __float22bfloat162_rn(make_float2(f0.z, f0.w));
                u.h[2] = __float22bfloat162_rn(make_float2(f1.x, f1.y));
                u.h[3] = __float22bfloat162_rn(make_float2(f1.z, f1.w));
                af[kt] = u.s;
            }
        } else {
            // enc half: wave-local LDS rows
            af[0] = *(const short8*)&encw[lr][hi * 8];
            af[1] = *(const short8*)&encw[lr][32 + hi * 8];
            // loo half: rebuild from enc + merged (f1,f2) of previous layer
#pragma unroll
            for (int kt = 2; kt < 4; ++kt) {
                float f1s[8], f2s[8];
#pragma unroll
                for (int j = 0; j < 8; ++j) { f1s[j] = NINF; f2s[j] = NINF; }
                int base = (kt - 2) * 16 + 4 * hi;    // float4 index: cols (kt-2)*32+hi*8 ..+7
#pragma unroll
                for (int w = 0; w < 4; ++w) {
                    const float4* fq = (const float4*)fbuf[(l + 1) & 1][w];
                    float4 q0 = fq[base + 0], q1 = fq[base + 1];
                    float4 q2 = fq[base + 2], q3 = fq[base + 3];
                    t2merge(f1s[0], f2s[0], q0.x, q0.y); t2merge(f1s[1], f2s[1], q0.z, q0.w);
                    t2merge(f1s[2], f2s[2], q1.x, q1.y); t2merge(f1s[3], f2s[3], q1.z, q1.w);
                    t2merge(f1s[4], f2s[4], q2.x, q2.y); t2merge(f1s[5], f2s[5], q2.z, q2.w);
                    t2merge(f1s[6], f2s[6], q3.x, q3.y); t2merge(f1s[7], f2s[7], q3.z, q3.w);
                }
                short8 e = *(const short8*)&encw[lr][(kt - 2) * 32 + hi * 8];
                float lo[8];
#pragma unroll
                for (int j = 0; j < 8; ++j) {
                    float m = b2f(e[j]) + maddA;
                    float sel = (m == f1s[j]) ? f2s[j] : f1s[j];  // exact-eq, bf16-consistent
                    lo[j] = fmaxf(fmaxf(sel, m + NEGV), 0.0f);
                }
                union { short8 s; __hip_bfloat162 h[4]; } u;
                u.h[0] = __float22bfloat162_rn(make_float2(lo[0], lo[1]));
                u.h[1] = __float22bfloat162_rn(make_float2(lo[2], lo[3]));
                u.h[2] = __float22bfloat162_rn(make_float2(lo[4], lo[5]));
                u.h[3] = __float22bfloat162_rn(make_float2(lo[6], lo[7]));
                af[kt] = u.s;
            }
        }

        // ---- MFMA: 4 col-tiles x 4 k-tiles, 16-row strip ----
        floatx4 acc[4];
#pragma unroll
        for (int ct = 0; ct < 4; ++ct) { floatx4 z = {0.f, 0.f, 0.f, 0.f}; acc[ct] = z; }
#pragma unroll
        for (int kt = 0; kt < 4; ++kt)
#pragma unroll
            for (int ct = 0; ct < 4; ++ct) {
                short8 bf = wfrag[(kt * 4 + hi) * 64 + ct * 16 + lr];
                acc[ct] = __builtin_amdgcn_mfma_f32_16x16x32_bf16(af[kt], bf, acc[ct], 0, 0, 0);
            }

        // ---- bias + LayerNorm + ReLU (in place); DPP all-reduce over 16 lr-lanes ----
        float4 bias = *(const float4*)(bsv + l * H2 + 4 * lr);
        float4 gwv  = *(const float4*)(lnw + l * H2 + 4 * lr);
        float4 gbv  = *(const float4*)(lnb + l * H2 + 4 * lr);
#pragma unroll
        for (int reg = 0; reg < 4; ++reg) {
            float x0 = acc[0][reg] + bias.x;
            float x1 = acc[1][reg] + bias.y;
            float x2 = acc[2][reg] + bias.z;
            float x3 = acc[3][reg] + bias.w;
            float s = sum16((x0 + x1) + (x2 + x3));
            float q = sum16((x0 * x0 + x1 * x1) + (x2 * x2 + x3 * x3));
            float mu  = s * (1.0f / 64.0f);
            float var = fmaxf(q * (1.0f / 64.0f) - mu * mu, 0.0f);
            float rstd = rsqrtf(var + EPSV);
            acc[0][reg] = fmaxf(gwv.x * (x0 - mu) * rstd + gbv.x, 0.0f);
            acc[1][reg] = fmaxf(gwv.y * (x1 - mu) * rstd + gbv.y, 0.0f);
            acc[2][reg] = fmaxf(gwv.z * (x2 - mu) * rstd + gbv.z, 0.0f);
            acc[3][reg] = fmaxf(gwv.w * (x3 - mu) * rstd + gbv.w, 0.0f);
        }

        if (l < DEPTH - 1) {
            // ---- pack enc -> wave-local LDS; strip top2 over bf16-rounded masked ----
            float t1v[4] = {NINF, NINF, NINF, NINF}, t2v[4] = {NINF, NINF, NINF, NINF};
#pragma unroll
            for (int reg = 0; reg < 4; ++reg) {
                float mk = ((wid * 16 + hi * 4 + reg) >= L) ? NEGV : 0.0f;
                BH4 we;
                we.a = __float22bfloat162_rn(make_float2(acc[0][reg], acc[1][reg]));
                we.b = __float22bfloat162_rn(make_float2(acc[2][reg], acc[3][reg]));
                *(BH4*)&encw[hi * 4 + reg][4 * lr] = we;
                // top2 on the SAME rounded values the consumer will read
                t2ins(t1v[0], t2v[0], __bfloat162float(we.a.x) + mk);
                t2ins(t1v[1], t2v[1], __bfloat162float(we.a.y) + mk);
                t2ins(t1v[2], t2v[2], __bfloat162float(we.b.x) + mk);
                t2ins(t1v[3], t2v[3], __bfloat162float(we.b.y) + mk);
            }
#pragma unroll
            for (int ct = 0; ct < 4; ++ct) {
                t2merge(t1v[ct], t2v[ct], __shfl_xor(t1v[ct], 16, 64), __shfl_xor(t2v[ct], 16, 64));
                t2merge(t1v[ct], t2v[ct], __shfl_xor(t1v[ct], 32, 64), __shfl_xor(t2v[ct], 32, 64));
            }
            if (hi == 0) {       // col c=4lr+ct pair at dwords 2c,2c+1
                float4 w0 = make_float4(t1v[0], t2v[0], t1v[1], t2v[1]);
                float4 w1 = make_float4(t1v[2], t2v[2], t1v[3], t2v[3]);
                ((float4*)fbuf[l & 1][wid])[2 * lr]     = w0;
                ((float4*)fbuf[l & 1][wid])[2 * lr + 1] = w1;
            }
            __syncthreads();     // publish fbuf[l&1] (enc is wave-local, no sync needed)
        } else {
            // ---- final layer: f32 strip top2 -> fbuf[0] -> merged loo/enc maxes ----
            float t1v[4], t2v[4];
#pragma unroll
            for (int ct = 0; ct < 4; ++ct) {
                float a1 = NINF, a2 = NINF;
#pragma unroll
                for (int reg = 0; reg < 4; ++reg) {
                    float mk = ((wid * 16 + hi * 4 + reg) >= L) ? NEGV : 0.0f;
                    t2ins(a1, a2, acc[ct][reg] + mk);
                }
                t2merge(a1, a2, __shfl_xor(a1, 16, 64), __shfl_xor(a2, 16, 64));
                t2merge(a1, a2, __shfl_xor(a1, 32, 64), __shfl_xor(a2, 32, 64));
                t1v[ct] = a1; t2v[ct] = a2;
            }
            if (hi == 0) {
                float4 w0 = make_float4(t1v[0], t2v[0], t1v[1], t2v[1]);
                float4 w1 = make_float4(t1v[2], t2v[2], t1v[3], t2v[3]);
                ((float4*)fbuf[0][wid])[2 * lr]     = w0;
                ((float4*)fbuf[0][wid])[2 * lr + 1] = w1;
            }
            __syncthreads();     // publish final-layer partial top2
            float f1v[4], f2v[4];
#pragma unroll
            for (int ct = 0; ct < 4; ++ct) { f1v[ct] = NINF; f2v[ct] = NINF; }
#pragma unroll
            for (int w = 0; w < 4; ++w)
#pragma unroll
                for (int ct = 0; ct < 4; ++ct) {
                    float2 p = ((const float2*)fbuf[0][w])[4 * lr + ct];
                    t2merge(f1v[ct], f2v[ct], p.x, p.y);
                }
#pragma unroll
            for (int ct = 0; ct < 4; ++ct) {
                float e0 = NINF, l0 = NINF;
#pragma unroll
                for (int reg = 0; reg < 4; ++reg) {
                    float e = acc[ct][reg];
                    e0 = fmaxf(e0, e);
                    float mk = ((wid * 16 + hi * 4 + reg) >= L) ? NEGV : 0.0f;
                    float mv = e + mk;
                    float v = (mv == f1v[ct]) ? f2v[ct] : f1v[ct];
                    v = fmaxf(v, mv + NEGV);
                    l0 = fmaxf(l0, fmaxf(v, 0.0f));
                }
                e0 = fmaxf(e0, __shfl_xor(e0, 16, 64));
                e0 = fmaxf(e0, __shfl_xor(e0, 32, 64));
                l0 = fmaxf(l0, __shfl_xor(l0, 16, 64));
                l0 = fmaxf(l0, __shfl_xor(l0, 32, 64));
                em[ct] = e0; lm[ct] = l0;
            }
        }
    }

    // ---- cross-wave output merge ----
    if (hi == 0) {
        *(float4*)&obuf[wid][4 * lr]      = make_float4(em[0], em[1], em[2], em[3]);
        *(float4*)&obuf[wid][64 + 4 * lr] = make_float4(lm[0], lm[1], lm[2], lm[3]);
    }
    __syncthreads();
    if (t < Hd) {
        float v = fmaxf(fmaxf(obuf[0][t], obuf[1][t]), fmaxf(obuf[2][t], obuf[3][t]));
        out[(size_t)b * Hd + t] = v;
    }
}

extern "C" void kernel_launch(void* const* d_in, const int* in_sizes, int n_in,
                              void* d_out, int out_size, void* d_ws, size_t ws_size,
                              hipStream_t stream) {
    const float* hidden = (const float*)d_in[0];
    const int*   lvn    = (const int*)d_in[1];
    const float* Ws     = (const float*)d_in[2];
    const float* bs     = (const float*)d_in[3];
    const float* lnwp   = (const float*)d_in[4];
    const float* lnbp   = (const float*)d_in[5];
    unsigned short* wt  = (unsigned short*)d_ws;   // 48 KB bf16 fragment-packed W
    float* outp = (float*)d_out;

    prep_w<<<(DEPTH * 8192 + 255) / 256, 256, 0, stream>>>(Ws, wt);
    subgraph_kernel<<<Bsz, 256, 0, stream>>>(hidden, lvn, wt, bs, lnwp, lnbp, outp);
}

// Round 15
// 69.184 us; speedup vs baseline: 1.5047x; 1.5047x over previous
//
#include <hip/hip_runtime.h>
#include <hip/hip_bf16.h>

#define NEGV (-10000.0f)
#define EPSV (1e-5f)
#define NINF (-3.4e38f)

typedef __attribute__((ext_vector_type(8))) short short8;
typedef __attribute__((ext_vector_type(4))) float floatx4;

constexpr int Bsz = 4096, Nv = 64, Hd = 128, DEPTH = 3, H2 = 64;
constexpr int ESTR = 72;   // enc row stride bf16: 144 B (b128-aligned rows)

struct alignas(8) BH4 { __hip_bfloat162 a, b; };

__device__ __forceinline__ unsigned short f2b(float f) {
    unsigned int u = __builtin_bit_cast(unsigned int, f);
    u += 0x7fffu + ((u >> 16) & 1u);          // RNE to bf16
    return (unsigned short)(u >> 16);
}
__device__ __forceinline__ float b2f(short s) {
    unsigned int u = ((unsigned int)(unsigned short)s) << 16;
    return __builtin_bit_cast(float, u);
}

// 16-lane all-reduce sum on the VALU via DPP (no LDS pipe)
template <int CTRL>
__device__ __forceinline__ float dpp_add(float v) {
    int y = __builtin_amdgcn_update_dpp(0, __builtin_bit_cast(int, v), CTRL, 0xf, 0xf, true);
    return v + __builtin_bit_cast(float, y);
}
__device__ __forceinline__ float sum16(float v) {
    v = dpp_add<0xB1>(v);    // quad_perm [1,0,3,2]  (xor 1)
    v = dpp_add<0x4E>(v);    // quad_perm [2,3,0,1]  (xor 2)
    v = dpp_add<0x124>(v);   // row_ror:4
    v = dpp_add<0x128>(v);   // row_ror:8
    return v;
}

// top-2 helpers (duplicate-preserving, matches jax top_k semantics)
__device__ __forceinline__ void t2ins(float& t1, float& t2, float v) {
    float lo = fminf(t1, v); t1 = fmaxf(t1, v); t2 = fmaxf(t2, lo);
}
__device__ __forceinline__ void t2merge(float& t1, float& t2, float o1, float o2) {
    float lo = fminf(t1, o1); t1 = fmaxf(t1, o1); t2 = fmaxf(fmaxf(t2, o2), lo);
}

// Pack W[l] (128x64 f32) into bf16 MFMA-fragment order WITH column permutation:
// fragment position (ct,lr) sources actual column 4*lr+ct, so D-lane lr owns
// 4 consecutive output columns across its 4 accumulators.
__global__ void prep_w(const float* __restrict__ Ws, unsigned short* __restrict__ wt) {
    int idx = blockIdx.x * 256 + threadIdx.x;
    if (idx < DEPTH * 8192) {
        int l = idx >> 13, o = idx & 8191;
        int j = o & 7, q = (o >> 3) & 63, hi = (o >> 9) & 3, kt = o >> 11;
        int k = kt * 32 + hi * 8 + j;
        int srccol = (q & 15) * 4 + (q >> 4);
        wt[idx] = f2b(Ws[l * 8192 + k * 64 + srccol]);
    }
}

// NOTE: deliberately NO __launch_bounds__ — every cap we tried below the HW
// register-allocation step (R8/R12/R13/R14) induced scratch spill (WRITE_SIZE
// 18-215 MB). Unconstrained, the kernel needs ~108 unified regs -> 128-step
// -> 4 waves/EU naturally, spill-free.
__global__
void subgraph_kernel(const float* __restrict__ hidden, const int* __restrict__ lvn,
                     const unsigned short* __restrict__ wt,
                     const float* __restrict__ bsv, const float* __restrict__ lnw,
                     const float* __restrict__ lnb, float* __restrict__ out)
{
    // block = 2 polylines, 4 waves; wave w owns rows w*16..w*16+15 of BOTH.
    // Two independent per-poly chains per wave = ILP to fill VALU stalls.
    __shared__ __hip_bfloat16 encs[2][4][16][ESTR];  // [poly][wave][row][col] 18432 B
    __shared__ float fbuf[2][4][128];                // per-wave partial (f1,f2)  4096 B
    __shared__ float2 mbuf[2][64];                   // merged (f1,f2) per col    1024 B
    __shared__ float obuf[2][4][128];                // per-wave enc/loo maxes    4096 B

    const int t = threadIdx.x;
    const int lane = t & 63, wid = t >> 6;
    const int b0 = blockIdx.x * 2;
    const int lr = lane & 15, hi = lane >> 4;
    const int L0 = lvn[b0], L1 = lvn[b0 + 1];
    const int arow = wid * 16 + lr;                  // this lane's A-row
    const float mA[2] = {(arow >= L0) ? NEGV : 0.0f, (arow >= L1) ? NEGV : 0.0f};

    const float4* ab0 = (const float4*)(hidden + (size_t)b0 * Nv * Hd);
    const float4* ab1 = ab0 + (Nv * Hd) / 4;

    float em[2][4], lm[2][4];

#pragma unroll
    for (int l = 0; l < DEPTH; ++l) {
        const short8* wfrag = (const short8*)(wt + l * 8192);

        // ---- A fragments for both polylines ----
        short8 af[2][4];
        if (l == 0) {
#pragma unroll
            for (int p = 0; p < 2; ++p) {
                const float4* ab = p ? ab1 : ab0;
#pragma unroll
                for (int kt = 0; kt < 4; ++kt) {
                    int fi = arow * 32 + kt * 8 + hi * 2;
                    float4 f0 = ab[fi], f1 = ab[fi + 1];
                    union { short8 s; __hip_bfloat162 h[4]; } u;
                    u.h[0] = __float22bfloat162_rn(make_float2(f0.x, f0.y));
                    u.h[1] = __float22bfloat162_rn(make_float2(f0.z, f0.w));
                    u.h[2] = __float22bfloat162_rn(make_float2(f1.x, f1.y));
                    u.h[3] = __float22bfloat162_rn(make_float2(f1.z, f1.w));
                    af[p][kt] = u.s;
                }
            }
        } else {
            // enc half: wave-local LDS rows
#pragma unroll
            for (int p = 0; p < 2; ++p) {
                af[p][0] = *(const short8*)&encs[p][wid][lr][hi * 8];
                af[p][1] = *(const short8*)&encs[p][wid][lr][32 + hi * 8];
            }
            // loo half: rebuild from enc + MERGED (f1,f2) read straight from mbuf
#pragma unroll
            for (int kt = 2; kt < 4; ++kt) {
                int base = (kt - 2) * 16 + hi * 4;   // float4 idx into mbuf (2 cols / float4)
#pragma unroll
                for (int p = 0; p < 2; ++p) {
                    const float4* mq = (const float4*)mbuf[p];
                    float4 q0 = mq[base + 0], q1 = mq[base + 1];
                    float4 q2 = mq[base + 2], q3 = mq[base + 3];
                    float f1s[8] = {q0.x, q0.z, q1.x, q1.z, q2.x, q2.z, q3.x, q3.z};
                    float f2s[8] = {q0.y, q0.w, q1.y, q1.w, q2.y, q2.w, q3.y, q3.w};
                    short8 e = *(const short8*)&encs[p][wid][lr][(kt - 2) * 32 + hi * 8];
                    float lo[8];
#pragma unroll
                    for (int j = 0; j < 8; ++j) {
                        float m = b2f(e[j]) + mA[p];
                        float sel = (m == f1s[j]) ? f2s[j] : f1s[j];  // exact-eq, bf16-consistent
                        lo[j] = fmaxf(fmaxf(sel, m + NEGV), 0.0f);
                    }
                    union { short8 s; __hip_bfloat162 h[4]; } u;
                    u.h[0] = __float22bfloat162_rn(make_float2(lo[0], lo[1]));
                    u.h[1] = __float22bfloat162_rn(make_float2(lo[2], lo[3]));
                    u.h[2] = __float22bfloat162_rn(make_float2(lo[4], lo[5]));
                    u.h[3] = __float22bfloat162_rn(make_float2(lo[6], lo[7]));
                    af[p][kt] = u.s;
                }
            }
        }

        // ---- MFMA: B-frag shared by both polylines ----
        floatx4 acc[2][4];
#pragma unroll
        for (int p = 0; p < 2; ++p)
#pragma unroll
            for (int ct = 0; ct < 4; ++ct) { floatx4 z = {0.f, 0.f, 0.f, 0.f}; acc[p][ct] = z; }
#pragma unroll
        for (int kt = 0; kt < 4; ++kt)
#pragma unroll
            for (int ct = 0; ct < 4; ++ct) {
                short8 bf = wfrag[(kt * 4 + hi) * 64 + ct * 16 + lr];
                acc[0][ct] = __builtin_amdgcn_mfma_f32_16x16x32_bf16(af[0][kt], bf, acc[0][ct], 0, 0, 0);
                acc[1][ct] = __builtin_amdgcn_mfma_f32_16x16x32_bf16(af[1][kt], bf, acc[1][ct], 0, 0, 0);
            }

        // ---- bias + LayerNorm + ReLU (in place); DPP all-reduce; both polys ----
        float4 bias = *(const float4*)(bsv + l * H2 + 4 * lr);
        float4 gwv  = *(const float4*)(lnw + l * H2 + 4 * lr);
        float4 gbv  = *(const float4*)(lnb + l * H2 + 4 * lr);
#pragma unroll
        for (int p = 0; p < 2; ++p)
#pragma unroll
            for (int reg = 0; reg < 4; ++reg) {
                float x0 = acc[p][0][reg] + bias.x;
                float x1 = acc[p][1][reg] + bias.y;
                float x2 = acc[p][2][reg] + bias.z;
                float x3 = acc[p][3][reg] + bias.w;
                float s = sum16((x0 + x1) + (x2 + x3));
                float q = sum16((x0 * x0 + x1 * x1) + (x2 * x2 + x3 * x3));
                float mu  = s * (1.0f / 64.0f);
                float var = fmaxf(q * (1.0f / 64.0f) - mu * mu, 0.0f);
                float rstd = rsqrtf(var + EPSV);
                acc[p][0][reg] = fmaxf(gwv.x * (x0 - mu) * rstd + gbv.x, 0.0f);
                acc[p][1][reg] = fmaxf(gwv.y * (x1 - mu) * rstd + gbv.y, 0.0f);
                acc[p][2][reg] = fmaxf(gwv.z * (x2 - mu) * rstd + gbv.z, 0.0f);
                acc[p][3][reg] = fmaxf(gwv.w * (x3 - mu) * rstd + gbv.w, 0.0f);
            }

        // ---- strip top2 partials (+ enc pack to LDS for non-final layers) ----
        if (l < DEPTH - 1) {
#pragma unroll
            for (int p = 0; p < 2; ++p) {
                const int Lp = p ? L1 : L0;
                float t1v[4] = {NINF, NINF, NINF, NINF}, t2v[4] = {NINF, NINF, NINF, NINF};
#pragma unroll
                for (int reg = 0; reg < 4; ++reg) {
                    float mk = ((wid * 16 + hi * 4 + reg) >= Lp) ? NEGV : 0.0f;
                    BH4 we;
                    we.a = __float22bfloat162_rn(make_float2(acc[p][0][reg], acc[p][1][reg]));
                    we.b = __float22bfloat162_rn(make_float2(acc[p][2][reg], acc[p][3][reg]));
                    *(BH4*)&encs[p][wid][hi * 4 + reg][4 * lr] = we;
                    // top2 on the SAME rounded values the consumer will read
                    t2ins(t1v[0], t2v[0], __bfloat162float(we.a.x) + mk);
                    t2ins(t1v[1], t2v[1], __bfloat162float(we.a.y) + mk);
                    t2ins(t1v[2], t2v[2], __bfloat162float(we.b.x) + mk);
                    t2ins(t1v[3], t2v[3], __bfloat162float(we.b.y) + mk);
                }
#pragma unroll
                for (int ct = 0; ct < 4; ++ct) {
                    t2merge(t1v[ct], t2v[ct], __shfl_xor(t1v[ct], 16, 64), __shfl_xor(t2v[ct], 16, 64));
                    t2merge(t1v[ct], t2v[ct], __shfl_xor(t1v[ct], 32, 64), __shfl_xor(t2v[ct], 32, 64));
                }
                if (hi == 0) {   // float2 idx 4lr+ct <-> actual col 4lr+ct
                    ((float4*)fbuf[p][wid])[2 * lr]     = make_float4(t1v[0], t2v[0], t1v[1], t2v[1]);
                    ((float4*)fbuf[p][wid])[2 * lr + 1] = make_float4(t1v[2], t2v[2], t1v[3], t2v[3]);
                }
            }
        } else {
            // final layer: f32 top2 partials (no enc storage)
#pragma unroll
            for (int p = 0; p < 2; ++p) {
                const int Lp = p ? L1 : L0;
                float t1v[4], t2v[4];
#pragma unroll
                for (int ct = 0; ct < 4; ++ct) {
                    float a1 = NINF, a2 = NINF;
#pragma unroll
                    for (int reg = 0; reg < 4; ++reg) {
                        float mk = ((wid * 16 + hi * 4 + reg) >= Lp) ? NEGV : 0.0f;
                        t2ins(a1, a2, acc[p][ct][reg] + mk);
                    }
                    t2merge(a1, a2, __shfl_xor(a1, 16, 64), __shfl_xor(a2, 16, 64));
                    t2merge(a1, a2, __shfl_xor(a1, 32, 64), __shfl_xor(a2, 32, 64));
                    t1v[ct] = a1; t2v[ct] = a2;
                }
                if (hi == 0) {
                    ((float4*)fbuf[p][wid])[2 * lr]     = make_float4(t1v[0], t2v[0], t1v[1], t2v[1]);
                    ((float4*)fbuf[p][wid])[2 * lr + 1] = make_float4(t1v[2], t2v[2], t1v[3], t2v[3]);
                }
            }
        }
        __syncthreads();                     // publish partials (mbuf consumption done above)

        // ---- merge-once: wave p merges poly p's 4 partials, lane = column ----
        if (wid < 2) {
            float m1 = NINF, m2 = NINF;
#pragma unroll
            for (int w = 0; w < 4; ++w) {
                float2 pr = ((const float2*)fbuf[wid][w])[lane];
                t2merge(m1, m2, pr.x, pr.y);
            }
            mbuf[wid][lane] = make_float2(m1, m2);
        }
        __syncthreads();                     // publish merged (f1,f2)

        if (l == DEPTH - 1) {
            // ---- epilogue: enc/loo strip maxes from merged top2 ----
#pragma unroll
            for (int p = 0; p < 2; ++p) {
                const int Lp = p ? L1 : L0;
                const float4* mq = (const float4*)mbuf[p];
                float4 h0 = mq[2 * lr], h1 = mq[2 * lr + 1];
                float f1v[4] = {h0.x, h0.z, h1.x, h1.z};
                float f2v[4] = {h0.y, h0.w, h1.y, h1.w};
#pragma unroll
                for (int ct = 0; ct < 4; ++ct) {
                    float e0 = NINF, l0 = NINF;
#pragma unroll
                    for (int reg = 0; reg < 4; ++reg) {
                        float e = acc[p][ct][reg];
                        e0 = fmaxf(e0, e);
                        float mk = ((wid * 16 + hi * 4 + reg) >= Lp) ? NEGV : 0.0f;
                        float mv = e + mk;
                        float v = (mv == f1v[ct]) ? f2v[ct] : f1v[ct];
                        v = fmaxf(v, mv + NEGV);
                        l0 = fmaxf(l0, fmaxf(v, 0.0f));
                    }
                    e0 = fmaxf(e0, __shfl_xor(e0, 16, 64));
                    e0 = fmaxf(e0, __shfl_xor(e0, 32, 64));
                    l0 = fmaxf(l0, __shfl_xor(l0, 16, 64));
                    l0 = fmaxf(l0, __shfl_xor(l0, 32, 64));
                    em[p][ct] = e0; lm[p][ct] = l0;
                }
            }
        }
    }

    // ---- cross-wave output merge for both polylines ----
    if (hi == 0) {
#pragma unroll
        for (int p = 0; p < 2; ++p) {
            *(float4*)&obuf[p][wid][4 * lr]      = make_float4(em[p][0], em[p][1], em[p][2], em[p][3]);
            *(float4*)&obuf[p][wid][64 + 4 * lr] = make_float4(lm[p][0], lm[p][1], lm[p][2], lm[p][3]);
        }
    }
    __syncthreads();
    {
        int p = t >> 7, h = t & 127;
        float v = fmaxf(fmaxf(obuf[p][0][h], obuf[p][1][h]), fmaxf(obuf[p][2][h], obuf[p][3][h]));
        out[(size_t)(b0 + p) * Hd + h] = v;
    }
}

extern "C" void kernel_launch(void* const* d_in, const int* in_sizes, int n_in,
                              void* d_out, int out_size, void* d_ws, size_t ws_size,
                              hipStream_t stream) {
    const float* hidden = (const float*)d_in[0];
    const int*   lvn    = (const int*)d_in[1];
    const float* Ws     = (const float*)d_in[2];
    const float* bs     = (const float*)d_in[3];
    const float* lnwp   = (const float*)d_in[4];
    const float* lnbp   = (const float*)d_in[5];
    unsigned short* wt  = (unsigned short*)d_ws;   // 48 KB bf16 fragment-packed W
    float* outp = (float*)d_out;

    prep_w<<<(DEPTH * 8192 + 255) / 256, 256, 0, stream>>>(Ws, wt);
    subgraph_kernel<<<Bsz / 2, 256, 0, stream>>>(hidden, lvn, wt, bs, lnwp, lnbp, outp);
}

// Round 16
// 63.732 us; speedup vs baseline: 1.6334x; 1.0855x over previous
//
#include <hip/hip_runtime.h>
#include <hip/hip_bf16.h>

#define NEGV (-10000.0f)
#define EPSV (1e-5f)
#define NINF (-3.4e38f)

typedef __attribute__((ext_vector_type(8))) short short8;
typedef __attribute__((ext_vector_type(4))) float floatx4;

constexpr int Bsz = 4096, Nv = 64, Hd = 128, DEPTH = 3, H2 = 64;
constexpr int ESTR = 72;   // enc row stride bf16: 144 B (b128-aligned rows)

struct alignas(8) BH4 { __hip_bfloat162 a, b; };

__device__ __forceinline__ unsigned short f2b(float f) {
    unsigned int u = __builtin_bit_cast(unsigned int, f);
    u += 0x7fffu + ((u >> 16) & 1u);          // RNE to bf16
    return (unsigned short)(u >> 16);
}
__device__ __forceinline__ float b2f(short s) {
    unsigned int u = ((unsigned int)(unsigned short)s) << 16;
    return __builtin_bit_cast(float, u);
}

// 16-lane all-reduce sum on the VALU via DPP (no LDS pipe)
template <int CTRL>
__device__ __forceinline__ float dpp_add(float v) {
    int y = __builtin_amdgcn_update_dpp(0, __builtin_bit_cast(int, v), CTRL, 0xf, 0xf, true);
    return v + __builtin_bit_cast(float, y);
}
__device__ __forceinline__ float sum16(float v) {
    v = dpp_add<0xB1>(v);    // quad_perm [1,0,3,2]  (xor 1)
    v = dpp_add<0x4E>(v);    // quad_perm [2,3,0,1]  (xor 2)
    v = dpp_add<0x124>(v);   // row_ror:4
    v = dpp_add<0x128>(v);   // row_ror:8
    return v;
}

// top-2 helpers (duplicate-preserving, matches jax top_k semantics)
__device__ __forceinline__ void t2ins(float& t1, float& t2, float v) {
    float lo = fminf(t1, v); t1 = fmaxf(t1, v); t2 = fmaxf(t2, lo);
}
__device__ __forceinline__ void t2merge(float& t1, float& t2, float o1, float o2) {
    float lo = fminf(t1, o1); t1 = fmaxf(t1, o1); t2 = fmaxf(fmaxf(t2, o2), lo);
}

// Pack W[l] (128x64 f32) into bf16 MFMA-fragment order WITH column permutation:
// fragment position (ct,lr) sources actual column 4*lr+ct, so D-lane lr owns
// 4 consecutive output columns across its 4 accumulators.
__global__ void prep_w(const float* __restrict__ Ws, unsigned short* __restrict__ wt) {
    int idx = blockIdx.x * 256 + threadIdx.x;
    if (idx < DEPTH * 8192) {
        int l = idx >> 13, o = idx & 8191;
        int j = o & 7, q = (o >> 3) & 63, hi = (o >> 9) & 3, kt = o >> 11;
        int k = kt * 32 + hi * 8 + j;
        int srccol = (q & 15) * 4 + (q >> 4);
        wt[idx] = f2b(Ws[l * 8192 + k * 64 + srccol]);
    }
}

// bounds=3 is the only spill-free cap measured for this structure (~108 unified regs).
__global__ __launch_bounds__(256, 3)
void subgraph_kernel(const float* __restrict__ hidden, const int* __restrict__ lvn,
                     const unsigned short* __restrict__ wt,
                     const float* __restrict__ bsv, const float* __restrict__ lnw,
                     const float* __restrict__ lnb, float* __restrict__ out)
{
    // block = 2 polylines, 4 waves; wave w owns rows w*16..w*16+15 of BOTH.
    __shared__ __hip_bfloat16 encs[2][4][16][ESTR];  // [poly][wave][row][col] 18432 B
    __shared__ float fbuf3[4][4][2][2][64];          // [w][hi][p][plane t1/t2][col] 16384 B
    __shared__ float2 mbuf[2][64];                   // merged (f1,f2) per col    1024 B
    __shared__ float obuf[2][4][128];                // per-wave enc/loo maxes    4096 B

    const int t = threadIdx.x;
    const int lane = t & 63, wid = t >> 6;
    const int b0 = blockIdx.x * 2;
    const int lr = lane & 15, hi = lane >> 4;
    const int L0 = lvn[b0], L1 = lvn[b0 + 1];
    const int arow = wid * 16 + lr;                  // this lane's A-row
    const float mA[2] = {(arow >= L0) ? NEGV : 0.0f, (arow >= L1) ? NEGV : 0.0f};

    const float4* ab0 = (const float4*)(hidden + (size_t)b0 * Nv * Hd);
    const float4* ab1 = ab0 + (Nv * Hd) / 4;

    float em[2][4], lm[2][4];

#pragma unroll
    for (int l = 0; l < DEPTH; ++l) {
        const short8* wfrag = (const short8*)(wt + l * 8192);

        // ---- A fragments for both polylines ----
        short8 af[2][4];
        if (l == 0) {
#pragma unroll
            for (int p = 0; p < 2; ++p) {
                const float4* ab = p ? ab1 : ab0;
#pragma unroll
                for (int kt = 0; kt < 4; ++kt) {
                    int fi = arow * 32 + kt * 8 + hi * 2;
                    float4 f0 = ab[fi], f1 = ab[fi + 1];
                    union { short8 s; __hip_bfloat162 h[4]; } u;
                    u.h[0] = __float22bfloat162_rn(make_float2(f0.x, f0.y));
                    u.h[1] = __float22bfloat162_rn(make_float2(f0.z, f0.w));
                    u.h[2] = __float22bfloat162_rn(make_float2(f1.x, f1.y));
                    u.h[3] = __float22bfloat162_rn(make_float2(f1.z, f1.w));
                    af[p][kt] = u.s;
                }
            }
        } else {
            // enc half: wave-local LDS rows
#pragma unroll
            for (int p = 0; p < 2; ++p) {
                af[p][0] = *(const short8*)&encs[p][wid][lr][hi * 8];
                af[p][1] = *(const short8*)&encs[p][wid][lr][32 + hi * 8];
            }
            // loo half: rebuild from enc + MERGED (f1,f2) read straight from mbuf.
            // loo = max(sel, m+NEGV, 0) == max(sel, 0) since |enc| <= 63/8 << 1e4
            // (LayerNorm bound) makes m+NEGV < 0 always.
#pragma unroll
            for (int kt = 2; kt < 4; ++kt) {
                int base = (kt - 2) * 16 + hi * 4;   // float4 idx into mbuf (2 cols / float4)
#pragma unroll
                for (int p = 0; p < 2; ++p) {
                    const float4* mq = (const float4*)mbuf[p];
                    float4 q0 = mq[base + 0], q1 = mq[base + 1];
                    float4 q2 = mq[base + 2], q3 = mq[base + 3];
                    float f1s[8] = {q0.x, q0.z, q1.x, q1.z, q2.x, q2.z, q3.x, q3.z};
                    float f2s[8] = {q0.y, q0.w, q1.y, q1.w, q2.y, q2.w, q3.y, q3.w};
                    short8 e = *(const short8*)&encs[p][wid][lr][(kt - 2) * 32 + hi * 8];
                    float lo[8];
#pragma unroll
                    for (int j = 0; j < 8; ++j) {
                        float m = b2f(e[j]) + mA[p];
                        float sel = (m == f1s[j]) ? f2s[j] : f1s[j];  // exact-eq, bf16-consistent
                        lo[j] = fmaxf(sel, 0.0f);
                    }
                    union { short8 s; __hip_bfloat162 h[4]; } u;
                    u.h[0] = __float22bfloat162_rn(make_float2(lo[0], lo[1]));
                    u.h[1] = __float22bfloat162_rn(make_float2(lo[2], lo[3]));
                    u.h[2] = __float22bfloat162_rn(make_float2(lo[4], lo[5]));
                    u.h[3] = __float22bfloat162_rn(make_float2(lo[6], lo[7]));
                    af[p][kt] = u.s;
                }
            }
        }

        // ---- MFMA: B-frag shared by both polylines ----
        floatx4 acc[2][4];
#pragma unroll
        for (int p = 0; p < 2; ++p)
#pragma unroll
            for (int ct = 0; ct < 4; ++ct) { floatx4 z = {0.f, 0.f, 0.f, 0.f}; acc[p][ct] = z; }
#pragma unroll
        for (int kt = 0; kt < 4; ++kt)
#pragma unroll
            for (int ct = 0; ct < 4; ++ct) {
                short8 bf = wfrag[(kt * 4 + hi) * 64 + ct * 16 + lr];
                acc[0][ct] = __builtin_amdgcn_mfma_f32_16x16x32_bf16(af[0][kt], bf, acc[0][ct], 0, 0, 0);
                acc[1][ct] = __builtin_amdgcn_mfma_f32_16x16x32_bf16(af[1][kt], bf, acc[1][ct], 0, 0, 0);
            }

        // ---- bias + LayerNorm + ReLU (in place); DPP all-reduce; both polys ----
        float4 bias = *(const float4*)(bsv + l * H2 + 4 * lr);
        float4 gwv  = *(const float4*)(lnw + l * H2 + 4 * lr);
        float4 gbv  = *(const float4*)(lnb + l * H2 + 4 * lr);
#pragma unroll
        for (int p = 0; p < 2; ++p)
#pragma unroll
            for (int reg = 0; reg < 4; ++reg) {
                float x0 = acc[p][0][reg] + bias.x;
                float x1 = acc[p][1][reg] + bias.y;
                float x2 = acc[p][2][reg] + bias.z;
                float x3 = acc[p][3][reg] + bias.w;
                float s = sum16((x0 + x1) + (x2 + x3));
                float q = sum16((x0 * x0 + x1 * x1) + (x2 * x2 + x3 * x3));
                float mu  = s * (1.0f / 64.0f);
                float var = fmaxf(q * (1.0f / 64.0f) - mu * mu, 0.0f);
                float rstd = rsqrtf(var + EPSV);
                acc[p][0][reg] = fmaxf(gwv.x * (x0 - mu) * rstd + gbv.x, 0.0f);
                acc[p][1][reg] = fmaxf(gwv.y * (x1 - mu) * rstd + gbv.y, 0.0f);
                acc[p][2][reg] = fmaxf(gwv.z * (x2 - mu) * rstd + gbv.z, 0.0f);
                acc[p][3][reg] = fmaxf(gwv.w * (x3 - mu) * rstd + gbv.w, 0.0f);
            }

        // ---- strip top2 partials per (wave,hi) -> fbuf3 (no shfl butterflies) ----
        if (l < DEPTH - 1) {
#pragma unroll
            for (int p = 0; p < 2; ++p) {
                const int Lp = p ? L1 : L0;
                float t1v[4] = {NINF, NINF, NINF, NINF}, t2v[4] = {NINF, NINF, NINF, NINF};
#pragma unroll
                for (int reg = 0; reg < 4; ++reg) {
                    float mk = ((wid * 16 + hi * 4 + reg) >= Lp) ? NEGV : 0.0f;
                    BH4 we;
                    we.a = __float22bfloat162_rn(make_float2(acc[p][0][reg], acc[p][1][reg]));
                    we.b = __float22bfloat162_rn(make_float2(acc[p][2][reg], acc[p][3][reg]));
                    *(BH4*)&encs[p][wid][hi * 4 + reg][4 * lr] = we;
                    // top2 on the SAME rounded values the consumer will read
                    t2ins(t1v[0], t2v[0], __bfloat162float(we.a.x) + mk);
                    t2ins(t1v[1], t2v[1], __bfloat162float(we.a.y) + mk);
                    t2ins(t1v[2], t2v[2], __bfloat162float(we.b.x) + mk);
                    t2ins(t1v[3], t2v[3], __bfloat162float(we.b.y) + mk);
                }
                // lane owns cols 4lr..4lr+3 -> contiguous float4, all hi write
                *(float4*)&fbuf3[wid][hi][p][0][4 * lr] = make_float4(t1v[0], t1v[1], t1v[2], t1v[3]);
                *(float4*)&fbuf3[wid][hi][p][1][4 * lr] = make_float4(t2v[0], t2v[1], t2v[2], t2v[3]);
            }
        } else {
            // final layer: f32 top2 partials (no enc storage)
#pragma unroll
            for (int p = 0; p < 2; ++p) {
                const int Lp = p ? L1 : L0;
                float t1v[4], t2v[4];
#pragma unroll
                for (int ct = 0; ct < 4; ++ct) {
                    float a1 = NINF, a2 = NINF;
#pragma unroll
                    for (int reg = 0; reg < 4; ++reg) {
                        float mk = ((wid * 16 + hi * 4 + reg) >= Lp) ? NEGV : 0.0f;
                        t2ins(a1, a2, acc[p][ct][reg] + mk);
                    }
                    t1v[ct] = a1; t2v[ct] = a2;
                }
                *(float4*)&fbuf3[wid][hi][p][0][4 * lr] = make_float4(t1v[0], t1v[1], t1v[2], t1v[3]);
                *(float4*)&fbuf3[wid][hi][p][1][4 * lr] = make_float4(t2v[0], t2v[1], t2v[2], t2v[3]);
            }
        }
        __syncthreads();                     // publish partials (mbuf consumption done above)

        // ---- merge-once: 128 threads, 1 column each, 16 (t1,t2) pairs ----
        if (t < 128) {
            int p = t >> 6, c = t & 63;
            float m1 = NINF, m2 = NINF;
#pragma unroll
            for (int w = 0; w < 4; ++w)
#pragma unroll
                for (int h = 0; h < 4; ++h)
                    t2merge(m1, m2, fbuf3[w][h][p][0][c], fbuf3[w][h][p][1][c]);
            mbuf[p][c] = make_float2(m1, m2);
        }
        __syncthreads();                     // publish merged (f1,f2)

        if (l == DEPTH - 1) {
            // ---- epilogue: enc/loo strip maxes from merged top2 ----
#pragma unroll
            for (int p = 0; p < 2; ++p) {
                const int Lp = p ? L1 : L0;
                const float4* mq = (const float4*)mbuf[p];
                float4 h0 = mq[2 * lr], h1 = mq[2 * lr + 1];
                float f1v[4] = {h0.x, h0.z, h1.x, h1.z};
                float f2v[4] = {h0.y, h0.w, h1.y, h1.w};
#pragma unroll
                for (int ct = 0; ct < 4; ++ct) {
                    float e0 = NINF, l0 = NINF;
#pragma unroll
                    for (int reg = 0; reg < 4; ++reg) {
                        float e = acc[p][ct][reg];
                        e0 = fmaxf(e0, e);
                        float mk = ((wid * 16 + hi * 4 + reg) >= Lp) ? NEGV : 0.0f;
                        float mv = e + mk;
                        float v = (mv == f1v[ct]) ? f2v[ct] : f1v[ct];
                        l0 = fmaxf(l0, fmaxf(v, 0.0f));   // m+NEGV term dead (LN bound)
                    }
                    e0 = fmaxf(e0, __shfl_xor(e0, 16, 64));
                    e0 = fmaxf(e0, __shfl_xor(e0, 32, 64));
                    l0 = fmaxf(l0, __shfl_xor(l0, 16, 64));
                    l0 = fmaxf(l0, __shfl_xor(l0, 32, 64));
                    em[p][ct] = e0; lm[p][ct] = l0;
                }
            }
        }
    }

    // ---- cross-wave output merge for both polylines ----
    if (hi == 0) {
#pragma unroll
        for (int p = 0; p < 2; ++p) {
            *(float4*)&obuf[p][wid][4 * lr]      = make_float4(em[p][0], em[p][1], em[p][2], em[p][3]);
            *(float4*)&obuf[p][wid][64 + 4 * lr] = make_float4(lm[p][0], lm[p][1], lm[p][2], lm[p][3]);
        }
    }
    __syncthreads();
    {
        int p = t >> 7, h = t & 127;
        float v = fmaxf(fmaxf(obuf[p][0][h], obuf[p][1][h]), fmaxf(obuf[p][2][h], obuf[p][3][h]));
        out[(size_t)(b0 + p) * Hd + h] = v;
    }
}

extern "C" void kernel_launch(void* const* d_in, const int* in_sizes, int n_in,
                              void* d_out, int out_size, void* d_ws, size_t ws_size,
                              hipStream_t stream) {
    const float* hidden = (const float*)d_in[0];
    const int*   lvn    = (const int*)d_in[1];
    const float* Ws     = (const float*)d_in[2];
    const float* bs     = (const float*)d_in[3];
    const float* lnwp   = (const float*)d_in[4];
    const float* lnbp   = (const float*)d_in[5];
    unsigned short* wt  = (unsigned short*)d_ws;   // 48 KB bf16 fragment-packed W
    float* outp = (float*)d_out;

    prep_w<<<(DEPTH * 8192 + 255) / 256, 256, 0, stream>>>(Ws, wt);
    subgraph_kernel<<<Bsz / 2, 256, 0, stream>>>(hidden, lvn, wt, bs, lnwp, lnbp, outp);
}

// Round 17
// 56.211 us; speedup vs baseline: 1.8519x; 1.1338x over previous
//
#include <hip/hip_runtime.h>
#include <hip/hip_bf16.h>

#define NEGV (-10000.0f)
#define EPSV (1e-5f)
#define NINF (-3.4e38f)

typedef __attribute__((ext_vector_type(8))) short short8;
typedef __attribute__((ext_vector_type(4))) float floatx4;

constexpr int Bsz = 4096, Nv = 64, Hd = 128, DEPTH = 3, H2 = 64;
constexpr int ESTR = 72;   // enc row stride bf16: 144 B (b128-aligned rows)

struct alignas(8) BH4 { __hip_bfloat162 a, b; };

__device__ __forceinline__ unsigned short f2b(float f) {
    unsigned int u = __builtin_bit_cast(unsigned int, f);
    u += 0x7fffu + ((u >> 16) & 1u);          // RNE to bf16
    return (unsigned short)(u >> 16);
}

// 16-lane all-reduce sum on the VALU via DPP (no LDS pipe)
template <int CTRL>
__device__ __forceinline__ float dpp_add(float v) {
    int y = __builtin_amdgcn_update_dpp(0, __builtin_bit_cast(int, v), CTRL, 0xf, 0xf, true);
    return v + __builtin_bit_cast(float, y);
}
__device__ __forceinline__ float sum16(float v) {
    v = dpp_add<0xB1>(v);    // quad_perm [1,0,3,2]  (xor 1)
    v = dpp_add<0x4E>(v);    // quad_perm [2,3,0,1]  (xor 2)
    v = dpp_add<0x124>(v);   // row_ror:4
    v = dpp_add<0x128>(v);   // row_ror:8
    return v;
}

// top-2 with argmax-index tracking. Tie rows are safe with ANY index choice:
// tie => f2==f1 numerically => the select is value-identical (exact).
__device__ __forceinline__ void t2insIdx(float& t1, float& t2, unsigned& i1,
                                         float v, unsigned iv) {
    bool c = v > t1;
    float lo = fminf(t1, v);
    t1 = fmaxf(t1, v);
    i1 = c ? iv : i1;
    t2 = fmaxf(t2, lo);
}

// Pack W[l] (128x64 f32) into bf16 MFMA-fragment order WITH column permutation:
// fragment position (ct,lr) sources actual column 4*lr+ct, so D-lane lr owns
// 4 consecutive output columns across its 4 accumulators.
__global__ void prep_w(const float* __restrict__ Ws, unsigned short* __restrict__ wt) {
    int idx = blockIdx.x * 256 + threadIdx.x;
    if (idx < DEPTH * 8192) {
        int l = idx >> 13, o = idx & 8191;
        int j = o & 7, q = (o >> 3) & 63, hi = (o >> 9) & 3, kt = o >> 11;
        int k = kt * 32 + hi * 8 + j;
        int srccol = (q & 15) * 4 + (q >> 4);
        wt[idx] = f2b(Ws[l * 8192 + k * 64 + srccol]);
    }
}

// bounds=3 is the only spill-free cap measured for this structure.
__global__ __launch_bounds__(256, 3)
void subgraph_kernel(const float* __restrict__ hidden, const int* __restrict__ lvn,
                     const unsigned short* __restrict__ wt,
                     const float* __restrict__ bsv, const float* __restrict__ lnw,
                     const float* __restrict__ lnb, float* __restrict__ out)
{
    // block = 2 polylines, 4 waves; wave w owns rows w*16..w*16+15 of BOTH.
    __shared__ __hip_bfloat16 encs[2][4][16][ESTR];  // [poly][wave][row][col] 18432 B
    __shared__ float fbuf3[4][4][2][3][64];          // [w][hi][p][plane][col]  24576 B
    __shared__ float apk[2][64][2];                  // bf16-packed (F1,F2) u32s 1024 B
    __shared__ unsigned short aidx[2][64];           // argmax row per column     256 B

    const int t = threadIdx.x;
    const int lane = t & 63, wid = t >> 6;
    const int b0 = blockIdx.x * 2;
    const int lr = lane & 15, hi = lane >> 4;
    const int L0 = lvn[b0], L1 = lvn[b0 + 1];
    const unsigned myrow = wid * 16 + lr;            // this lane's A-row

    // hoisted pad-mask addend per (poly, reg): row = wid*16 + hi*4 + reg
    float madd[2][4];
#pragma unroll
    for (int p = 0; p < 2; ++p)
#pragma unroll
        for (int reg = 0; reg < 4; ++reg)
            madd[p][reg] = ((int)(wid * 16 + hi * 4 + reg) >= (p ? L1 : L0)) ? NEGV : 0.0f;

    const float4* ab0 = (const float4*)(hidden + (size_t)b0 * Nv * Hd);
    const float4* ab1 = ab0 + (Nv * Hd) / 4;

#pragma unroll
    for (int l = 0; l < DEPTH; ++l) {
        const short8* wfrag = (const short8*)(wt + l * 8192);

        // ---- A fragments for both polylines ----
        short8 af[2][4];
        if (l == 0) {
#pragma unroll
            for (int p = 0; p < 2; ++p) {
                const float4* ab = p ? ab1 : ab0;
#pragma unroll
                for (int kt = 0; kt < 4; ++kt) {
                    int fi = (int)myrow * 32 + kt * 8 + hi * 2;
                    float4 f0 = ab[fi], f1 = ab[fi + 1];
                    union { short8 s; __hip_bfloat162 h[4]; } u;
                    u.h[0] = __float22bfloat162_rn(make_float2(f0.x, f0.y));
                    u.h[1] = __float22bfloat162_rn(make_float2(f0.z, f0.w));
                    u.h[2] = __float22bfloat162_rn(make_float2(f1.x, f1.y));
                    u.h[3] = __float22bfloat162_rn(make_float2(f1.z, f1.w));
                    af[p][kt] = u.s;
                }
            }
        } else {
            // enc half: wave-local LDS rows
#pragma unroll
            for (int p = 0; p < 2; ++p) {
                af[p][0] = *(const short8*)&encs[p][wid][lr][hi * 8];
                af[p][1] = *(const short8*)&encs[p][wid][lr][32 + hi * 8];
            }
            // loo half: select pre-rounded F1/F2 by argmax-index compare.
            // loo[r][c] = (r==argrow_c) ? max(f2,0) : max(f1,0); the m+NEGV
            // clamp is dead (LN bound |enc| <= 63/8 << 1e4).
#pragma unroll
            for (int kt = 2; kt < 4; ++kt) {
                int cbase = (kt - 2) * 32 + hi * 8;
#pragma unroll
                for (int p = 0; p < 2; ++p) {
                    short8 ar = *(const short8*)&aidx[p][cbase];
                    const float4* ap = (const float4*)&apk[p][0][0];
                    int fb = cbase >> 1;                 // float4 = 2 cols
                    float4 q0 = ap[fb], q1 = ap[fb + 1], q2 = ap[fb + 2], q3 = ap[fb + 3];
                    unsigned pk1s[8] = {
                        __builtin_bit_cast(unsigned, q0.x), __builtin_bit_cast(unsigned, q0.z),
                        __builtin_bit_cast(unsigned, q1.x), __builtin_bit_cast(unsigned, q1.z),
                        __builtin_bit_cast(unsigned, q2.x), __builtin_bit_cast(unsigned, q2.z),
                        __builtin_bit_cast(unsigned, q3.x), __builtin_bit_cast(unsigned, q3.z)};
                    unsigned pk2s[8] = {
                        __builtin_bit_cast(unsigned, q0.y), __builtin_bit_cast(unsigned, q0.w),
                        __builtin_bit_cast(unsigned, q1.y), __builtin_bit_cast(unsigned, q1.w),
                        __builtin_bit_cast(unsigned, q2.y), __builtin_bit_cast(unsigned, q2.w),
                        __builtin_bit_cast(unsigned, q3.y), __builtin_bit_cast(unsigned, q3.w)};
                    union { short8 s; unsigned u[4]; } uu;
#pragma unroll
                    for (int j2 = 0; j2 < 4; ++j2) {
                        unsigned s0 = ((unsigned)(unsigned short)ar[2 * j2]     == myrow)
                                      ? pk2s[2 * j2]     : pk1s[2 * j2];
                        unsigned s1 = ((unsigned)(unsigned short)ar[2 * j2 + 1] == myrow)
                                      ? pk2s[2 * j2 + 1] : pk1s[2 * j2 + 1];
                        uu.u[j2] = __builtin_amdgcn_perm(s1, s0, 0x05040100u);
                    }
                    af[p][kt] = uu.s;
                }
            }
        }

        // ---- MFMA: B-frag shared by both polylines ----
        floatx4 acc[2][4];
#pragma unroll
        for (int p = 0; p < 2; ++p)
#pragma unroll
            for (int ct = 0; ct < 4; ++ct) { floatx4 z = {0.f, 0.f, 0.f, 0.f}; acc[p][ct] = z; }
#pragma unroll
        for (int kt = 0; kt < 4; ++kt)
#pragma unroll
            for (int ct = 0; ct < 4; ++ct) {
                short8 bf = wfrag[(kt * 4 + hi) * 64 + ct * 16 + lr];
                acc[0][ct] = __builtin_amdgcn_mfma_f32_16x16x32_bf16(af[0][kt], bf, acc[0][ct], 0, 0, 0);
                acc[1][ct] = __builtin_amdgcn_mfma_f32_16x16x32_bf16(af[1][kt], bf, acc[1][ct], 0, 0, 0);
            }

        // ---- bias + LayerNorm + ReLU (in place); DPP all-reduce; both polys ----
        float4 bias = *(const float4*)(bsv + l * H2 + 4 * lr);
        float4 gwv  = *(const float4*)(lnw + l * H2 + 4 * lr);
        float4 gbv  = *(const float4*)(lnb + l * H2 + 4 * lr);
#pragma unroll
        for (int p = 0; p < 2; ++p)
#pragma unroll
            for (int reg = 0; reg < 4; ++reg) {
                float x0 = acc[p][0][reg] + bias.x;
                float x1 = acc[p][1][reg] + bias.y;
                float x2 = acc[p][2][reg] + bias.z;
                float x3 = acc[p][3][reg] + bias.w;
                float s = sum16((x0 + x1) + (x2 + x3));
                float q = sum16((x0 * x0 + x1 * x1) + (x2 * x2 + x3 * x3));
                float mu  = s * (1.0f / 64.0f);
                float var = fmaxf(q * (1.0f / 64.0f) - mu * mu, 0.0f);
                float rstd = rsqrtf(var + EPSV);
                acc[p][0][reg] = fmaxf(gwv.x * (x0 - mu) * rstd + gbv.x, 0.0f);
                acc[p][1][reg] = fmaxf(gwv.y * (x1 - mu) * rstd + gbv.y, 0.0f);
                acc[p][2][reg] = fmaxf(gwv.z * (x2 - mu) * rstd + gbv.z, 0.0f);
                acc[p][3][reg] = fmaxf(gwv.w * (x3 - mu) * rstd + gbv.w, 0.0f);
            }

        if (l < DEPTH - 1) {
            // ---- enc pack -> wave-local LDS; f32 masked top2 WITH index ----
#pragma unroll
            for (int p = 0; p < 2; ++p) {
                float t1v[4] = {NINF, NINF, NINF, NINF}, t2v[4] = {NINF, NINF, NINF, NINF};
                unsigned i1v[4] = {0, 0, 0, 0};
#pragma unroll
                for (int reg = 0; reg < 4; ++reg) {
                    BH4 we;
                    we.a = __float22bfloat162_rn(make_float2(acc[p][0][reg], acc[p][1][reg]));
                    we.b = __float22bfloat162_rn(make_float2(acc[p][2][reg], acc[p][3][reg]));
                    *(BH4*)&encs[p][wid][hi * 4 + reg][4 * lr] = we;
                    float mk = madd[p][reg];
                    unsigned rowi = wid * 16 + hi * 4 + reg;
                    t2insIdx(t1v[0], t2v[0], i1v[0], acc[p][0][reg] + mk, rowi);
                    t2insIdx(t1v[1], t2v[1], i1v[1], acc[p][1][reg] + mk, rowi);
                    t2insIdx(t1v[2], t2v[2], i1v[2], acc[p][2][reg] + mk, rowi);
                    t2insIdx(t1v[3], t2v[3], i1v[3], acc[p][3][reg] + mk, rowi);
                }
                *(float4*)&fbuf3[wid][hi][p][0][4 * lr] = make_float4(t1v[0], t1v[1], t1v[2], t1v[3]);
                *(float4*)&fbuf3[wid][hi][p][1][4 * lr] = make_float4(t2v[0], t2v[1], t2v[2], t2v[3]);
                *(float4*)&fbuf3[wid][hi][p][2][4 * lr] = make_float4(
                    __builtin_bit_cast(float, i1v[0]), __builtin_bit_cast(float, i1v[1]),
                    __builtin_bit_cast(float, i1v[2]), __builtin_bit_cast(float, i1v[3]));
            }
            __syncthreads();                 // publish partials

            // ---- merge-once: 128 threads, 1 column each; pre-round F1/F2 ----
            if (t < 128) {
                int p = t >> 6, c = t & 63;
                float m1 = NINF, m2 = NINF; unsigned a1 = 0;
#pragma unroll
                for (int w = 0; w < 4; ++w)
#pragma unroll
                    for (int h = 0; h < 4; ++h) {
                        float o1 = fbuf3[w][h][p][0][c], o2 = fbuf3[w][h][p][1][c];
                        unsigned io = __builtin_bit_cast(unsigned, fbuf3[w][h][p][2][c]);
                        bool cg = o1 > m1;
                        float lo = fminf(m1, o1);
                        m1 = fmaxf(m1, o1);
                        a1 = cg ? io : a1;
                        m2 = fmaxf(fmaxf(m2, o2), lo);
                    }
                float F1 = fmaxf(m1, 0.0f), F2 = fmaxf(m2, 0.0f);
                apk[p][c][0] = __builtin_bit_cast(float, (unsigned)f2b(F1));
                apk[p][c][1] = __builtin_bit_cast(float, (unsigned)f2b(F2));
                aidx[p][c] = (unsigned short)a1;
            }
            __syncthreads();                 // publish merged selects
        } else {
            // ---- FINAL layer: out_loo[c] = max(f1_c,0) EXACTLY (>=1 non-argmax
            // row always; all-tie => f2==f1). out_enc[c] = unmasked enc max.
            // No per-row selects, no shuffles, no epilogue.
#pragma unroll
            for (int p = 0; p < 2; ++p) {
                float t1v[4], em4[4];
#pragma unroll
                for (int ct = 0; ct < 4; ++ct) {
                    float a = acc[p][ct][0], b = acc[p][ct][1];
                    float c2 = acc[p][ct][2], d = acc[p][ct][3];
                    em4[ct] = fmaxf(fmaxf(a, b), fmaxf(c2, d));
                    t1v[ct] = fmaxf(fmaxf(a + madd[p][0], b + madd[p][1]),
                                    fmaxf(c2 + madd[p][2], d + madd[p][3]));
                }
                *(float4*)&fbuf3[wid][hi][p][0][4 * lr] = make_float4(t1v[0], t1v[1], t1v[2], t1v[3]);
                *(float4*)&fbuf3[wid][hi][p][1][4 * lr] = make_float4(em4[0], em4[1], em4[2], em4[3]);
            }
            __syncthreads();                 // publish partials

            if (t < 128) {
                int p = t >> 6, c = t & 63;
                float mm = NINF, me = NINF;
#pragma unroll
                for (int w = 0; w < 4; ++w)
#pragma unroll
                    for (int h = 0; h < 4; ++h) {
                        mm = fmaxf(mm, fbuf3[w][h][p][0][c]);
                        me = fmaxf(me, fbuf3[w][h][p][1][c]);
                    }
                out[(size_t)(b0 + p) * Hd + c]      = me;             // enc half
                out[(size_t)(b0 + p) * Hd + 64 + c] = fmaxf(mm, 0.0f); // loo half
            }
        }
    }
}

extern "C" void kernel_launch(void* const* d_in, const int* in_sizes, int n_in,
                              void* d_out, int out_size, void* d_ws, size_t ws_size,
                              hipStream_t stream) {
    const float* hidden = (const float*)d_in[0];
    const int*   lvn    = (const int*)d_in[1];
    const float* Ws     = (const float*)d_in[2];
    const float* bs     = (const float*)d_in[3];
    const float* lnwp   = (const float*)d_in[4];
    const float* lnbp   = (const float*)d_in[5];
    unsigned short* wt  = (unsigned short*)d_ws;   // 48 KB bf16 fragment-packed W
    float* outp = (float*)d_out;

    prep_w<<<(DEPTH * 8192 + 255) / 256, 256, 0, stream>>>(Ws, wt);
    subgraph_kernel<<<Bsz / 2, 256, 0, stream>>>(hidden, lvn, wt, bs, lnwp, lnbp, outp);
}